// Round 4
// baseline (245.715 us; speedup 1.0000x reference)
//
#include <hip/hip_runtime.h>

#define CCH   256
#define NSEQ  4096
#define NH    8
#define HD    32

typedef short s8x __attribute__((ext_vector_type(8)));
typedef float f4x __attribute__((ext_vector_type(4)));

__device__ __forceinline__ f4x mfma16(s8x a, s8x b, f4x c) {
  return __builtin_amdgcn_mfma_f32_16x16x32_bf16(a, b, c, 0, 0, 0);
}

__device__ __forceinline__ unsigned short f2bf(float f) {
  union { float f; unsigned int u; } v; v.f = f;
  unsigned int u = v.u + 0x7fffu + ((v.u >> 16) & 1u);
  return (unsigned short)(u >> 16);
}

// pack two f32 -> one u32 of bf16 (truncating; P >= 0 so safe)
__device__ __forceinline__ unsigned int pk_bf_trunc(float lo, float hi) {
  union { float f; unsigned int u; } a, b; a.f = lo; b.f = hi;
  return __builtin_amdgcn_perm(b.u, a.u, 0x07060302);
}

// raw v_exp_f32
#if defined(__has_builtin)
#if __has_builtin(__builtin_amdgcn_exp2f)
#define FEXP2(x) __builtin_amdgcn_exp2f(x)
#endif
#endif
#ifndef FEXP2
__device__ __forceinline__ float __fexp2_asm(float x) {
  float r; asm("v_exp_f32 %0, %1" : "=v"(r) : "v"(x)); return r;
}
#define FEXP2(x) __fexp2_asm(x)
#endif

#define C2SCALE (0.17677669529663689f * 1.4426950408889634f)

// ---------------- weight fp32 -> bf16 ----------------
__global__ __launch_bounds__(256) void cvt_weights(const float* __restrict__ qw,
                                                   const float* __restrict__ pw,
                                                   unsigned short* __restrict__ qwb,
                                                   unsigned short* __restrict__ pwb) {
  const int t = blockIdx.x * 256 + threadIdx.x;   // 0..65535
  const float4* src;
  unsigned short* dst;
  int idx;
  if (t < 49152) { src = reinterpret_cast<const float4*>(qw); dst = qwb; idx = t; }
  else           { src = reinterpret_cast<const float4*>(pw); dst = pwb; idx = t - 49152; }
  const float4 vv = src[idx];
  union { unsigned short u[4]; uint2 v; } pk;
  pk.u[0] = f2bf(vv.x); pk.u[1] = f2bf(vv.y); pk.u[2] = f2bf(vv.z); pk.u[3] = f2bf(vv.w);
  *reinterpret_cast<uint2*>(dst + 4 * idx) = pk.v;
}

// ---------------- LayerNorm + transpose ----------------
__global__ __launch_bounds__(256) void ln_kernel(const float* __restrict__ x,
                                                 const float* __restrict__ nw,
                                                 const float* __restrict__ nb,
                                                 unsigned short* __restrict__ xn) {
  __shared__ float Ls[256 * 32];
  __shared__ float Sred[2][32][8];
  const int t  = threadIdx.x;
  const int n  = t & 31;
  const int cg = t >> 5;
  const int p0 = blockIdx.x * 32;
  const int b  = p0 >> 12;
  const int n0 = p0 & 4095;
  const float* xb = x + (size_t)b * CCH * NSEQ + n0;

  #pragma unroll
  for (int i = 0; i < 32; ++i) {
    const int c = i * 8 + cg;
    Ls[c * 32 + (n ^ (c & 31))] = xb[(size_t)c * NSEQ + n];
  }
  __syncthreads();

  float s = 0.f, sq = 0.f;
  #pragma unroll
  for (int j = 0; j < 32; ++j) {
    const int c = cg * 32 + j;
    const float v = Ls[c * 32 + (n ^ j)];
    s += v; sq += v * v;
  }
  Sred[0][n][cg] = s; Sred[1][n][cg] = sq;
  __syncthreads();
  float ts = 0.f, tq = 0.f;
  #pragma unroll
  for (int g = 0; g < 8; ++g) { ts += Sred[0][n][g]; tq += Sred[1][n][g]; }
  const float mean = ts * (1.f / 256.f);
  const float rstd = rsqrtf(tq * (1.f / 256.f) - mean * mean + 1e-5f);

  unsigned short* orow = xn + ((size_t)b * NSEQ + n0 + n) * CCH + cg * 32;
  #pragma unroll
  for (int j8 = 0; j8 < 4; ++j8) {
    unsigned int w_[4];
    #pragma unroll
    for (int hw = 0; hw < 4; ++hw) {
      const int j = j8 * 8 + hw * 2;
      const int c = cg * 32 + j;
      const float v0 = Ls[c * 32 + (n ^ j)];
      const float v1 = Ls[(c + 1) * 32 + (n ^ (j + 1))];
      const float y0 = (v0 - mean) * rstd * nw[c] + nb[c];
      const float y1 = (v1 - mean) * rstd * nw[c + 1] + nb[c + 1];
      w_[hw] = (unsigned int)f2bf(y0) | ((unsigned int)f2bf(y1) << 16);
    }
    uint4 pkv; pkv.x = w_[0]; pkv.y = w_[1]; pkv.z = w_[2]; pkv.w = w_[3];
    *reinterpret_cast<uint4*>(orow + j8 * 8) = pkv;
  }
}

// ======== shared LDS-tiled GEMM core: 128m x 64n tile, BK=64, K=256 ========
// As: 128x64 shorts, row r holds 8 chunks of 8 shorts, chunk c stored at c^(r&7).
// Staging loads are contiguous 1KiB/instr; frag reads are bank-balanced b128.
#define GEMM_CORE(A_PTR, B_PTR, ACC)                                            \
  {                                                                             \
    for (int kb = 0; kb < 4; ++kb) {                                            \
      if (kb) __syncthreads();                                                  \
      _Pragma("unroll")                                                         \
      for (int j = 0; j < 4; ++j) {                                             \
        const int c = j * 256 + tid;                                            \
        const int ar = c >> 3, acr = c & 7;                                     \
        *reinterpret_cast<s8x*>(&As[ar * 64 + ((acr ^ (ar & 7)) << 3)]) =       \
          *reinterpret_cast<const s8x*>(A_PTR + (size_t)(mt * 128 + ar) * CCH + kb * 64 + acr * 8); \
      }                                                                         \
      _Pragma("unroll")                                                         \
      for (int j = 0; j < 2; ++j) {                                             \
        const int c = j * 256 + tid;                                            \
        const int br = c >> 3, bcr = c & 7;                                     \
        *reinterpret_cast<s8x*>(&Bs[br * 64 + ((bcr ^ (br & 7)) << 3)]) =       \
          *reinterpret_cast<const s8x*>(B_PTR + (size_t)(nt * 64 + br) * CCH + kb * 64 + bcr * 8); \
      }                                                                         \
      __syncthreads();                                                          \
      _Pragma("unroll")                                                         \
      for (int kin = 0; kin < 2; ++kin) {                                       \
        const int chx = ((kin * 4 + quad) ^ (l16 & 7)) << 3;                    \
        const s8x a0 = *reinterpret_cast<const s8x*>(&As[(wv * 32 + l16) * 64 + chx]);      \
        const s8x a1 = *reinterpret_cast<const s8x*>(&As[(wv * 32 + 16 + l16) * 64 + chx]); \
        _Pragma("unroll")                                                       \
        for (int ni = 0; ni < 4; ++ni) {                                        \
          const s8x bf = *reinterpret_cast<const s8x*>(&Bs[(ni * 16 + l16) * 64 + chx]);    \
          ACC[0][ni] = mfma16(a0, bf, ACC[0][ni]);                              \
          ACC[1][ni] = mfma16(a1, bf, ACC[1][ni]);                              \
        }                                                                       \
      }                                                                         \
    }                                                                           \
  }

// ---------------- QKV GEMM (tiled) ----------------
// grid (64, 12): mt 128-row tiles, nt 64-col tiles of the 768 outputs.
__global__ __launch_bounds__(256, 3) void qkv_gemm(const unsigned short* __restrict__ xn,
                                                   const unsigned short* __restrict__ w,
                                                   const float* __restrict__ bias,
                                                   unsigned short* __restrict__ q,
                                                   unsigned short* __restrict__ k,
                                                   unsigned short* __restrict__ vt) {
  __shared__ unsigned short As[128 * 64];
  __shared__ unsigned short Bs[64 * 64];
  const int tid = threadIdx.x;
  const int wv  = tid >> 6;
  const int lane = tid & 63;
  const int quad = lane >> 4, l16 = lane & 15;
  const int mt = blockIdx.x;
  const int nt = blockIdx.y;

  f4x acc[2][4];
  #pragma unroll
  for (int mi = 0; mi < 2; ++mi)
    #pragma unroll
    for (int ni = 0; ni < 4; ++ni)
      acc[mi][ni] = (f4x){0.f, 0.f, 0.f, 0.f};

  GEMM_CORE(xn, w, acc)

  const int sel = nt >> 2;                  // wave-uniform: 0=q 1=k 2=v
  #pragma unroll
  for (int ni = 0; ni < 4; ++ni) {
    const int o = nt * 64 + ni * 16 + l16;
    const float bs = bias[o];
    const int ol = o & 255;
    const int head = ol >> 5, d = ol & 31;
    #pragma unroll
    for (int mi = 0; mi < 2; ++mi) {
      const int g0 = mt * 128 + wv * 32 + mi * 16 + quad * 4;
      const int bb = g0 >> 12, n0 = g0 & 4095;
      if (sel == 2) {
        unsigned short* vp = vt + ((size_t)(bb * NH + head) * HD + d) * NSEQ + n0;
        uint2 pk;
        pk.x = (unsigned int)f2bf(acc[mi][ni][0] + bs) | ((unsigned int)f2bf(acc[mi][ni][1] + bs) << 16);
        pk.y = (unsigned int)f2bf(acc[mi][ni][2] + bs) | ((unsigned int)f2bf(acc[mi][ni][3] + bs) << 16);
        *reinterpret_cast<uint2*>(vp) = pk;
      } else {
        const float sc = (sel == 0) ? C2SCALE : 1.f;
        unsigned short* base = (sel == 0) ? q : k;
        #pragma unroll
        for (int r = 0; r < 4; ++r)
          base[((size_t)(bb * NH + head) * NSEQ + n0 + r) * HD + d] = f2bf((acc[mi][ni][r] + bs) * sc);
      }
    }
  }
}

// ---------------- proj GEMM + residual (tiled) ----------------
// grid (64, 4)
__global__ __launch_bounds__(256, 3) void proj_gemm(const unsigned short* __restrict__ xa,
                                                    const unsigned short* __restrict__ w,
                                                    const float* __restrict__ bias,
                                                    const float* __restrict__ gamma,
                                                    const float* __restrict__ x,
                                                    float* __restrict__ out) {
  __shared__ unsigned short As[128 * 64];
  __shared__ unsigned short Bs[64 * 64];
  const int tid = threadIdx.x;
  const int wv  = tid >> 6;
  const int lane = tid & 63;
  const int quad = lane >> 4, l16 = lane & 15;
  const int mt = blockIdx.x;
  const int nt = blockIdx.y;

  f4x acc[2][4];
  #pragma unroll
  for (int mi = 0; mi < 2; ++mi)
    #pragma unroll
    for (int ni = 0; ni < 4; ++ni)
      acc[mi][ni] = (f4x){0.f, 0.f, 0.f, 0.f};

  GEMM_CORE(xa, w, acc)

  const float g0 = gamma[0];
  #pragma unroll
  for (int ni = 0; ni < 4; ++ni) {
    const int c = nt * 64 + ni * 16 + l16;
    const float bs = bias[c];
    #pragma unroll
    for (int mi = 0; mi < 2; ++mi) {
      const int gr = mt * 128 + wv * 32 + mi * 16 + quad * 4;
      const int bb = gr >> 12, n0 = gr & 4095;
      const size_t off = (size_t)(bb * CCH + c) * NSEQ + n0;
      const float4 xv = *reinterpret_cast<const float4*>(x + off);
      float4 ov;
      ov.x = g0 * (acc[mi][ni][0] + bs) + xv.x;
      ov.y = g0 * (acc[mi][ni][1] + bs) + xv.y;
      ov.z = g0 * (acc[mi][ni][2] + bs) + xv.z;
      ov.w = g0 * (acc[mi][ni][3] + bs) + xv.w;
      *reinterpret_cast<float4*>(out + off) = ov;
    }
  }
}

// ---------------- Flash attention (S^T, shift-free, barrier-free) ----------------
// grid (64 q-tiles of 64, 16 bh), 128 thr = 2 waves -> 1024 blocks = 8 blocks/CU
// = 16 waves/CU (2x R3 occupancy). Inner structure identical to R3.
__global__ __launch_bounds__(128, 4) void fa_kernel(const unsigned short* __restrict__ q,
                                                    const unsigned short* __restrict__ k,
                                                    const unsigned short* __restrict__ vt,
                                                    unsigned short* __restrict__ xa) {
  __shared__ unsigned short Ps[64 * 128];   // 16 KiB

  const int tid  = threadIdx.x;
  const int wv   = tid >> 6;     // 0..1
  const int lane = tid & 63;
  const int quad = lane >> 4;
  const int l16  = lane & 15;
  const int qblk = blockIdx.x;   // 0..63
  const int bh   = blockIdx.y;
  const int b    = bh >> 3;
  const int h    = bh & 7;

  const unsigned short* kb_ = k  + (size_t)bh * NSEQ * HD;
  const unsigned short* vb_ = vt + (size_t)bh * HD * NSEQ;

  s8x bq0, bq1;
  {
    const unsigned short* qb = q + ((size_t)bh * NSEQ + (size_t)qblk * 64 + wv * 32) * HD;
    bq0 = *reinterpret_cast<const s8x*>(qb + (size_t)l16 * HD + quad * 8);
    bq1 = *reinterpret_cast<const s8x*>(qb + (size_t)(16 + l16) * HD + quad * 8);
  }
  s8x ak[8];
  #pragma unroll
  for (int i = 0; i < 8; ++i)
    ak[i] = *reinterpret_cast<const s8x*>(kb_ + (size_t)(i * 16 + l16) * HD + quad * 8);
  s8x av[8];
  #pragma unroll
  for (int kb2 = 0; kb2 < 4; ++kb2) {
    av[kb2]     = *reinterpret_cast<const s8x*>(vb_ + (size_t)l16 * NSEQ + kb2 * 32 + quad * 8);
    av[4 + kb2] = *reinterpret_cast<const s8x*>(vb_ + (size_t)(16 + l16) * NSEQ + kb2 * 32 + quad * 8);
  }

  f4x oacc[2][2];
  #pragma unroll
  for (int dt = 0; dt < 2; ++dt)
    #pragma unroll
    for (int ct = 0; ct < 2; ++ct)
      oacc[dt][ct] = (f4x){0.f, 0.f, 0.f, 0.f};
  f4x accL[2] = {(f4x){0.f, 0.f, 0.f, 0.f}, (f4x){0.f, 0.f, 0.f, 0.f}};

  s8x ones;
  #pragma unroll
  for (int j = 0; j < 8; ++j) ones[j] = (short)0x3F80;

  for (int it = 0; it < NSEQ / 128; ++it) {
    f4x st[8][2];
    #pragma unroll
    for (int i = 0; i < 8; ++i) {
      const f4x z = {0.f, 0.f, 0.f, 0.f};
      st[i][0] = mfma16(ak[i], bq0, z);
      st[i][1] = mfma16(ak[i], bq1, z);
    }

    if (it + 1 < NSEQ / 128) {
      const unsigned short* kn = kb_ + (size_t)(it + 1) * 128 * HD;
      #pragma unroll
      for (int i = 0; i < 8; ++i)
        ak[i] = *reinterpret_cast<const s8x*>(kn + (size_t)(i * 16 + l16) * HD + quad * 8);
    }

    #pragma unroll
    for (int i = 0; i < 8; ++i)
      #pragma unroll
      for (int ct = 0; ct < 2; ++ct)
        #pragma unroll
        for (int r = 0; r < 4; ++r)
          st[i][ct][r] = FEXP2(st[i][ct][r]);

    #pragma unroll
    for (int ct = 0; ct < 2; ++ct) {
      const int qphys = wv * 32 + ct * 16 + l16;
      #pragma unroll
      for (int i = 0; i < 8; ++i) {
        uint2 pw;
        pw.x = pk_bf_trunc(st[i][ct][0], st[i][ct][1]);
        pw.y = pk_bf_trunc(st[i][ct][2], st[i][ct][3]);
        const int chunk = (2 * i + (quad >> 1)) ^ l16;
        *reinterpret_cast<uint2*>(&Ps[qphys * 128 + chunk * 8 + (quad & 1) * 4]) = pw;
      }
    }

    #pragma unroll
    for (int kb2 = 0; kb2 < 4; ++kb2) {
      const int ch = (4 * kb2 + quad) ^ l16;
      const s8x bp0 = *reinterpret_cast<const s8x*>(&Ps[(wv * 32 + l16) * 128 + ch * 8]);
      const s8x bp1 = *reinterpret_cast<const s8x*>(&Ps[(wv * 32 + 16 + l16) * 128 + ch * 8]);
      oacc[0][0] = mfma16(av[kb2],     bp0, oacc[0][0]);
      oacc[1][0] = mfma16(av[4 + kb2], bp0, oacc[1][0]);
      oacc[0][1] = mfma16(av[kb2],     bp1, oacc[0][1]);
      oacc[1][1] = mfma16(av[4 + kb2], bp1, oacc[1][1]);
      accL[0] = mfma16(ones, bp0, accL[0]);
      accL[1] = mfma16(ones, bp1, accL[1]);
    }

    if (it + 1 < NSEQ / 128) {
      const unsigned short* vn = vb_ + (size_t)(it + 1) * 128;
      #pragma unroll
      for (int kb2 = 0; kb2 < 4; ++kb2) {
        av[kb2]     = *reinterpret_cast<const s8x*>(vn + (size_t)l16 * NSEQ + kb2 * 32 + quad * 8);
        av[4 + kb2] = *reinterpret_cast<const s8x*>(vn + (size_t)(16 + l16) * NSEQ + kb2 * 32 + quad * 8);
      }
    }
  }

  #pragma unroll
  for (int ct = 0; ct < 2; ++ct) {
    const float il = 1.f / accL[ct][0];
    const int qg = qblk * 64 + wv * 32 + ct * 16 + l16;
    #pragma unroll
    for (int dt = 0; dt < 2; ++dt) {
      uint2 ow;
      ow.x = (unsigned int)f2bf(oacc[dt][ct][0] * il) |
             ((unsigned int)f2bf(oacc[dt][ct][1] * il) << 16);
      ow.y = (unsigned int)f2bf(oacc[dt][ct][2] * il) |
             ((unsigned int)f2bf(oacc[dt][ct][3] * il) << 16);
      unsigned short* dst = xa + ((size_t)b * NSEQ + qg) * CCH + h * HD + dt * 16 + quad * 4;
      *reinterpret_cast<uint2*>(dst) = ow;
    }
  }
}

extern "C" void kernel_launch(void* const* d_in, const int* in_sizes, int n_in,
                              void* d_out, int out_size, void* d_ws, size_t ws_size,
                              hipStream_t stream) {
  const float* x      = (const float*)d_in[0];
  const float* norm_w = (const float*)d_in[1];
  const float* norm_b = (const float*)d_in[2];
  const float* qkv_w  = (const float*)d_in[3];
  const float* qkv_b  = (const float*)d_in[4];
  const float* proj_w = (const float*)d_in[5];
  const float* proj_b = (const float*)d_in[6];
  const float* gamma  = (const float*)d_in[7];
  float* out = (float*)d_out;

  char* ws = (char*)d_ws;
  unsigned short* xn  = (unsigned short*)(ws);              // (B,N,C) bf16, 4 MiB
  unsigned short* qwb = (unsigned short*)(ws + 4194304);
  unsigned short* pwb = (unsigned short*)(ws + 4587520);
  unsigned short* q   = (unsigned short*)(ws + 4718592);    // (B,NH,N,HD), pre-scaled
  unsigned short* k   = (unsigned short*)(ws + 8912896);    // (B,NH,N,HD)
  unsigned short* vt  = (unsigned short*)(ws + 13107200);   // (B,NH,HD,N)
  unsigned short* xa  = (unsigned short*)(ws + 17301504);   // (B,N,C)

  hipLaunchKernelGGL(cvt_weights, dim3(256), dim3(256), 0, stream, qkv_w, proj_w, qwb, pwb);
  hipLaunchKernelGGL(ln_kernel,   dim3(256), dim3(256), 0, stream, x, norm_w, norm_b, xn);
  hipLaunchKernelGGL(qkv_gemm,    dim3(64, 12), dim3(256), 0, stream, xn, qwb, qkv_b, q, k, vt);
  hipLaunchKernelGGL(fa_kernel,   dim3(64, 16), dim3(128), 0, stream, q, k, vt, xa);
  hipLaunchKernelGGL(proj_gemm,   dim3(64, 4), dim3(256), 0, stream, xa, pwb, proj_b, gamma, x, out);
}

// Round 5
// 192.733 us; speedup vs baseline: 1.2749x; 1.2749x over previous
//
#include <hip/hip_runtime.h>

#define CCH   256
#define NSEQ  4096
#define NH    8
#define HD    32

typedef short s8x __attribute__((ext_vector_type(8)));
typedef float f4x __attribute__((ext_vector_type(4)));

__device__ __forceinline__ f4x mfma16(s8x a, s8x b, f4x c) {
  return __builtin_amdgcn_mfma_f32_16x16x32_bf16(a, b, c, 0, 0, 0);
}

__device__ __forceinline__ unsigned short f2bf(float f) {
  union { float f; unsigned int u; } v; v.f = f;
  unsigned int u = v.u + 0x7fffu + ((v.u >> 16) & 1u);
  return (unsigned short)(u >> 16);
}

__device__ __forceinline__ unsigned int pk_bf_rnd(float lo, float hi) {
  return (unsigned int)f2bf(lo) | ((unsigned int)f2bf(hi) << 16);
}

// pack two f32 -> one u32 of bf16 (truncating; P >= 0 so safe)
__device__ __forceinline__ unsigned int pk_bf_trunc(float lo, float hi) {
  union { float f; unsigned int u; } a, b; a.f = lo; b.f = hi;
  return __builtin_amdgcn_perm(b.u, a.u, 0x07060302);
}

// raw v_exp_f32
#if defined(__has_builtin)
#if __has_builtin(__builtin_amdgcn_exp2f)
#define FEXP2(x) __builtin_amdgcn_exp2f(x)
#endif
#endif
#ifndef FEXP2
__device__ __forceinline__ float __fexp2_asm(float x) {
  float r; asm("v_exp_f32 %0, %1" : "=v"(r) : "v"(x)); return r;
}
#define FEXP2(x) __fexp2_asm(x)
#endif

#define C2SCALE (0.17677669529663689f * 1.4426950408889634f)

// ---------------- weight fp32 -> bf16 ----------------
__global__ __launch_bounds__(256) void cvt_weights(const float* __restrict__ qw,
                                                   const float* __restrict__ pw,
                                                   unsigned short* __restrict__ qwb,
                                                   unsigned short* __restrict__ pwb) {
  const int t = blockIdx.x * 256 + threadIdx.x;   // 0..65535
  const float4* src;
  unsigned short* dst;
  int idx;
  if (t < 49152) { src = reinterpret_cast<const float4*>(qw); dst = qwb; idx = t; }
  else           { src = reinterpret_cast<const float4*>(pw); dst = pwb; idx = t - 49152; }
  const float4 vv = src[idx];
  union { unsigned short u[4]; uint2 v; } pk;
  pk.u[0] = f2bf(vv.x); pk.u[1] = f2bf(vv.y); pk.u[2] = f2bf(vv.z); pk.u[3] = f2bf(vv.w);
  *reinterpret_cast<uint2*>(dst + 4 * idx) = pk.v;
}

// ---------------- LayerNorm + transpose ----------------
__global__ __launch_bounds__(256) void ln_kernel(const float* __restrict__ x,
                                                 const float* __restrict__ nw,
                                                 const float* __restrict__ nb,
                                                 unsigned short* __restrict__ xn) {
  __shared__ float Ls[256 * 32];
  __shared__ float Sred[2][32][8];
  const int t  = threadIdx.x;
  const int n  = t & 31;
  const int cg = t >> 5;
  const int p0 = blockIdx.x * 32;
  const int b  = p0 >> 12;
  const int n0 = p0 & 4095;
  const float* xb = x + (size_t)b * CCH * NSEQ + n0;

  #pragma unroll
  for (int i = 0; i < 32; ++i) {
    const int c = i * 8 + cg;
    Ls[c * 32 + (n ^ (c & 31))] = xb[(size_t)c * NSEQ + n];
  }
  __syncthreads();

  float s = 0.f, sq = 0.f;
  #pragma unroll
  for (int j = 0; j < 32; ++j) {
    const int c = cg * 32 + j;
    const float v = Ls[c * 32 + (n ^ j)];
    s += v; sq += v * v;
  }
  Sred[0][n][cg] = s; Sred[1][n][cg] = sq;
  __syncthreads();
  float ts = 0.f, tq = 0.f;
  #pragma unroll
  for (int g = 0; g < 8; ++g) { ts += Sred[0][n][g]; tq += Sred[1][n][g]; }
  const float mean = ts * (1.f / 256.f);
  const float rstd = rsqrtf(tq * (1.f / 256.f) - mean * mean + 1e-5f);

  unsigned short* orow = xn + ((size_t)b * NSEQ + n0 + n) * CCH + cg * 32;
  #pragma unroll
  for (int j8 = 0; j8 < 4; ++j8) {
    unsigned int w_[4];
    #pragma unroll
    for (int hw = 0; hw < 4; ++hw) {
      const int j = j8 * 8 + hw * 2;
      const int c = cg * 32 + j;
      const float v0 = Ls[c * 32 + (n ^ j)];
      const float v1 = Ls[(c + 1) * 32 + (n ^ (j + 1))];
      const float y0 = (v0 - mean) * rstd * nw[c] + nb[c];
      const float y1 = (v1 - mean) * rstd * nw[c + 1] + nb[c + 1];
      w_[hw] = pk_bf_rnd(y0, y1);
    }
    uint4 pkv; pkv.x = w_[0]; pkv.y = w_[1]; pkv.z = w_[2]; pkv.w = w_[3];
    *reinterpret_cast<uint4*>(orow + j8 * 8) = pkv;
  }
}

// ======== shared LDS-tiled GEMM core: 128m x 64n tile, BK=64, K=256 ========
#define GEMM_CORE(A_PTR, B_PTR, ACC)                                            \
  {                                                                             \
    for (int kb = 0; kb < 4; ++kb) {                                            \
      if (kb) __syncthreads();                                                  \
      _Pragma("unroll")                                                         \
      for (int j = 0; j < 4; ++j) {                                             \
        const int c = j * 256 + tid;                                            \
        const int ar = c >> 3, acr = c & 7;                                     \
        *reinterpret_cast<s8x*>(&As[ar * 64 + ((acr ^ (ar & 7)) << 3)]) =       \
          *reinterpret_cast<const s8x*>(A_PTR + (size_t)(mt * 128 + ar) * CCH + kb * 64 + acr * 8); \
      }                                                                         \
      _Pragma("unroll")                                                         \
      for (int j = 0; j < 2; ++j) {                                             \
        const int c = j * 256 + tid;                                            \
        const int br = c >> 3, bcr = c & 7;                                     \
        *reinterpret_cast<s8x*>(&Bs[br * 64 + ((bcr ^ (br & 7)) << 3)]) =       \
          *reinterpret_cast<const s8x*>(B_PTR + (size_t)(nt * 64 + br) * CCH + kb * 64 + bcr * 8); \
      }                                                                         \
      __syncthreads();                                                          \
      _Pragma("unroll")                                                         \
      for (int kin = 0; kin < 2; ++kin) {                                       \
        const int chx = ((kin * 4 + quad) ^ (l16 & 7)) << 3;                    \
        const s8x a0 = *reinterpret_cast<const s8x*>(&As[(wv * 32 + l16) * 64 + chx]);      \
        const s8x a1 = *reinterpret_cast<const s8x*>(&As[(wv * 32 + 16 + l16) * 64 + chx]); \
        _Pragma("unroll")                                                       \
        for (int ni = 0; ni < 4; ++ni) {                                        \
          const s8x bf = *reinterpret_cast<const s8x*>(&Bs[(ni * 16 + l16) * 64 + chx]);    \
          ACC[0][ni] = mfma16(a0, bf, ACC[0][ni]);                              \
          ACC[1][ni] = mfma16(a1, bf, ACC[1][ni]);                              \
        }                                                                       \
      }                                                                         \
    }                                                                           \
  }

// ---------------- QKV GEMM (tiled) ----------------
__global__ __launch_bounds__(256, 3) void qkv_gemm(const unsigned short* __restrict__ xn,
                                                   const unsigned short* __restrict__ w,
                                                   const float* __restrict__ bias,
                                                   unsigned short* __restrict__ q,
                                                   unsigned short* __restrict__ k,
                                                   unsigned short* __restrict__ vt) {
  __shared__ unsigned short As[128 * 64];
  __shared__ unsigned short Bs[64 * 64];
  const int tid = threadIdx.x;
  const int wv  = tid >> 6;
  const int lane = tid & 63;
  const int quad = lane >> 4, l16 = lane & 15;
  const int mt = blockIdx.x;
  const int nt = blockIdx.y;

  f4x acc[2][4];
  #pragma unroll
  for (int mi = 0; mi < 2; ++mi)
    #pragma unroll
    for (int ni = 0; ni < 4; ++ni)
      acc[mi][ni] = (f4x){0.f, 0.f, 0.f, 0.f};

  GEMM_CORE(xn, w, acc)

  const int sel = nt >> 2;                  // wave-uniform: 0=q 1=k 2=v
  #pragma unroll
  for (int ni = 0; ni < 4; ++ni) {
    const int o = nt * 64 + ni * 16 + l16;
    const float bs = bias[o];
    const int ol = o & 255;
    const int head = ol >> 5, d = ol & 31;
    #pragma unroll
    for (int mi = 0; mi < 2; ++mi) {
      const int g0 = mt * 128 + wv * 32 + mi * 16 + quad * 4;
      const int bb = g0 >> 12, n0 = g0 & 4095;
      if (sel == 2) {
        unsigned short* vp = vt + ((size_t)(bb * NH + head) * HD + d) * NSEQ + n0;
        uint2 pk;
        pk.x = pk_bf_rnd(acc[mi][ni][0] + bs, acc[mi][ni][1] + bs);
        pk.y = pk_bf_rnd(acc[mi][ni][2] + bs, acc[mi][ni][3] + bs);
        *reinterpret_cast<uint2*>(vp) = pk;
      } else {
        const float sc = (sel == 0) ? C2SCALE : 1.f;
        unsigned short* base = (sel == 0) ? q : k;
        #pragma unroll
        for (int r = 0; r < 4; ++r)
          base[((size_t)(bb * NH + head) * NSEQ + n0 + r) * HD + d] = f2bf((acc[mi][ni][r] + bs) * sc);
      }
    }
  }
}

// ---------------- proj GEMM + residual (tiled) ----------------
__global__ __launch_bounds__(256, 3) void proj_gemm(const unsigned short* __restrict__ xa,
                                                    const unsigned short* __restrict__ w,
                                                    const float* __restrict__ bias,
                                                    const float* __restrict__ gamma,
                                                    const float* __restrict__ x,
                                                    float* __restrict__ out) {
  __shared__ unsigned short As[128 * 64];
  __shared__ unsigned short Bs[64 * 64];
  const int tid = threadIdx.x;
  const int wv  = tid >> 6;
  const int lane = tid & 63;
  const int quad = lane >> 4, l16 = lane & 15;
  const int mt = blockIdx.x;
  const int nt = blockIdx.y;

  f4x acc[2][4];
  #pragma unroll
  for (int mi = 0; mi < 2; ++mi)
    #pragma unroll
    for (int ni = 0; ni < 4; ++ni)
      acc[mi][ni] = (f4x){0.f, 0.f, 0.f, 0.f};

  GEMM_CORE(xa, w, acc)

  const float g0 = gamma[0];
  #pragma unroll
  for (int ni = 0; ni < 4; ++ni) {
    const int c = nt * 64 + ni * 16 + l16;
    const float bs = bias[c];
    #pragma unroll
    for (int mi = 0; mi < 2; ++mi) {
      const int gr = mt * 128 + wv * 32 + mi * 16 + quad * 4;
      const int bb = gr >> 12, n0 = gr & 4095;
      const size_t off = (size_t)(bb * CCH + c) * NSEQ + n0;
      const float4 xv = *reinterpret_cast<const float4*>(x + off);
      float4 ov;
      ov.x = g0 * (acc[mi][ni][0] + bs) + xv.x;
      ov.y = g0 * (acc[mi][ni][1] + bs) + xv.y;
      ov.z = g0 * (acc[mi][ni][2] + bs) + xv.z;
      ov.w = g0 * (acc[mi][ni][3] + bs) + xv.w;
      *reinterpret_cast<float4*>(out + off) = ov;
    }
  }
}

// ---------------- Flash attention (S^T, shift-free, split-KV) ----------------
// Flat grid 512*SPLIT blocks; bh = i&15 (same-bh blocks land on XCD bh%8 for
// L2 locality), qblk = (i>>4)&31, split = i>>9.  256 thr = 4 waves, q-tile 128.
// SPLIT>1: partial (unnormalized O fp32, l fp32) -> ws; fa_combine reduces.
template <int SPLIT>
__global__ __launch_bounds__(256, 2) void fa_kernel(const unsigned short* __restrict__ q,
                                                    const unsigned short* __restrict__ k,
                                                    const unsigned short* __restrict__ vt,
                                                    unsigned short* __restrict__ xa,
                                                    float* __restrict__ Op,
                                                    float* __restrict__ Lp) {
  constexpr int ITERS = NSEQ / 128 / SPLIT;
  __shared__ unsigned short Ps[128 * 128];   // 32 KiB

  const int tid  = threadIdx.x;
  const int wv   = tid >> 6;
  const int lane = tid & 63;
  const int quad = lane >> 4;
  const int l16  = lane & 15;
  const int i    = blockIdx.x;
  const int bh   = i & 15;
  const int qblk = (i >> 4) & 31;
  const int split = i >> 9;
  const int b    = bh >> 3;
  const int h    = bh & 7;
  const int kv0  = split * (NSEQ / SPLIT);

  const unsigned short* kb_ = k  + ((size_t)bh * NSEQ + kv0) * HD;
  const unsigned short* vb_ = vt + (size_t)bh * HD * NSEQ + kv0;

  s8x bq0, bq1;
  {
    const unsigned short* qb = q + ((size_t)bh * NSEQ + (size_t)qblk * 128 + wv * 32) * HD;
    bq0 = *reinterpret_cast<const s8x*>(qb + (size_t)l16 * HD + quad * 8);
    bq1 = *reinterpret_cast<const s8x*>(qb + (size_t)(16 + l16) * HD + quad * 8);
  }
  s8x ak[8];
  #pragma unroll
  for (int ii = 0; ii < 8; ++ii)
    ak[ii] = *reinterpret_cast<const s8x*>(kb_ + (size_t)(ii * 16 + l16) * HD + quad * 8);
  s8x av[8];
  #pragma unroll
  for (int kb2 = 0; kb2 < 4; ++kb2) {
    av[kb2]     = *reinterpret_cast<const s8x*>(vb_ + (size_t)l16 * NSEQ + kb2 * 32 + quad * 8);
    av[4 + kb2] = *reinterpret_cast<const s8x*>(vb_ + (size_t)(16 + l16) * NSEQ + kb2 * 32 + quad * 8);
  }

  f4x oacc[2][2];
  #pragma unroll
  for (int dt = 0; dt < 2; ++dt)
    #pragma unroll
    for (int ct = 0; ct < 2; ++ct)
      oacc[dt][ct] = (f4x){0.f, 0.f, 0.f, 0.f};
  f4x accL[2] = {(f4x){0.f, 0.f, 0.f, 0.f}, (f4x){0.f, 0.f, 0.f, 0.f}};

  s8x ones;
  #pragma unroll
  for (int j = 0; j < 8; ++j) ones[j] = (short)0x3F80;

  for (int it = 0; it < ITERS; ++it) {
    f4x st[8][2];
    #pragma unroll
    for (int ii = 0; ii < 8; ++ii) {
      const f4x z = {0.f, 0.f, 0.f, 0.f};
      st[ii][0] = mfma16(ak[ii], bq0, z);
      st[ii][1] = mfma16(ak[ii], bq1, z);
    }

    if (it + 1 < ITERS) {
      const unsigned short* kn = kb_ + (size_t)(it + 1) * 128 * HD;
      #pragma unroll
      for (int ii = 0; ii < 8; ++ii)
        ak[ii] = *reinterpret_cast<const s8x*>(kn + (size_t)(ii * 16 + l16) * HD + quad * 8);
    }

    #pragma unroll
    for (int ii = 0; ii < 8; ++ii)
      #pragma unroll
      for (int ct = 0; ct < 2; ++ct)
        #pragma unroll
        for (int r = 0; r < 4; ++r)
          st[ii][ct][r] = FEXP2(st[ii][ct][r]);

    #pragma unroll
    for (int ct = 0; ct < 2; ++ct) {
      const int qphys = wv * 32 + ct * 16 + l16;
      #pragma unroll
      for (int ii = 0; ii < 8; ++ii) {
        uint2 pw;
        pw.x = pk_bf_trunc(st[ii][ct][0], st[ii][ct][1]);
        pw.y = pk_bf_trunc(st[ii][ct][2], st[ii][ct][3]);
        const int chunk = (2 * ii + (quad >> 1)) ^ l16;
        *reinterpret_cast<uint2*>(&Ps[qphys * 128 + chunk * 8 + (quad & 1) * 4]) = pw;
      }
    }

    #pragma unroll
    for (int kb2 = 0; kb2 < 4; ++kb2) {
      const int ch = (4 * kb2 + quad) ^ l16;
      const s8x bp0 = *reinterpret_cast<const s8x*>(&Ps[(wv * 32 + l16) * 128 + ch * 8]);
      const s8x bp1 = *reinterpret_cast<const s8x*>(&Ps[(wv * 32 + 16 + l16) * 128 + ch * 8]);
      oacc[0][0] = mfma16(av[kb2],     bp0, oacc[0][0]);
      oacc[1][0] = mfma16(av[4 + kb2], bp0, oacc[1][0]);
      oacc[0][1] = mfma16(av[kb2],     bp1, oacc[0][1]);
      oacc[1][1] = mfma16(av[4 + kb2], bp1, oacc[1][1]);
      accL[0] = mfma16(ones, bp0, accL[0]);
      accL[1] = mfma16(ones, bp1, accL[1]);
    }

    if (it + 1 < ITERS) {
      const unsigned short* vn = vb_ + (size_t)(it + 1) * 128;
      #pragma unroll
      for (int kb2 = 0; kb2 < 4; ++kb2) {
        av[kb2]     = *reinterpret_cast<const s8x*>(vn + (size_t)l16 * NSEQ + kb2 * 32 + quad * 8);
        av[4 + kb2] = *reinterpret_cast<const s8x*>(vn + (size_t)(16 + l16) * NSEQ + kb2 * 32 + quad * 8);
      }
    }
  }

  if (SPLIT == 1) {
    #pragma unroll
    for (int ct = 0; ct < 2; ++ct) {
      const float il = 1.f / accL[ct][0];
      const int qg = qblk * 128 + wv * 32 + ct * 16 + l16;
      #pragma unroll
      for (int dt = 0; dt < 2; ++dt) {
        uint2 ow;
        ow.x = pk_bf_rnd(oacc[dt][ct][0] * il, oacc[dt][ct][1] * il);
        ow.y = pk_bf_rnd(oacc[dt][ct][2] * il, oacc[dt][ct][3] * il);
        unsigned short* dst = xa + ((size_t)b * NSEQ + qg) * CCH + h * HD + dt * 16 + quad * 4;
        *reinterpret_cast<uint2*>(dst) = ow;
      }
    }
  } else {
    #pragma unroll
    for (int ct = 0; ct < 2; ++ct) {
      const int qg = qblk * 128 + wv * 32 + ct * 16 + l16;
      float* ob = Op + (((size_t)(split * 16 + bh) * NSEQ) + qg) * HD;
      #pragma unroll
      for (int dt = 0; dt < 2; ++dt) {
        float4 w_;
        w_.x = oacc[dt][ct][0]; w_.y = oacc[dt][ct][1];
        w_.z = oacc[dt][ct][2]; w_.w = oacc[dt][ct][3];
        *reinterpret_cast<float4*>(ob + dt * 16 + quad * 4) = w_;
      }
      if (quad == 0)
        Lp[(size_t)split * 16 * NSEQ + (size_t)bh * NSEQ + qg] = accL[ct][0];
    }
  }
}

// ---------------- split-KV combine: xa = sum(Op)/sum(l) ----------------
// 131072 threads: g -> (bh, q, half16-of-d)
__global__ __launch_bounds__(256) void fa_combine(const float* __restrict__ Op,
                                                  const float* __restrict__ Lp,
                                                  unsigned short* __restrict__ xa,
                                                  int S) {
  const int g = blockIdx.x * 256 + threadIdx.x;
  const int half = g & 1;
  const int qq = (g >> 1) & 4095;
  const int bh = g >> 13;
  const int b = bh >> 3, h = bh & 7;
  const float* base = Op + ((size_t)bh * NSEQ + qq) * HD + half * 16;
  float acc[16];
  #pragma unroll
  for (int j = 0; j < 16; ++j) acc[j] = 0.f;
  float l = 0.f;
  for (int s = 0; s < S; ++s) {
    const float* p = base + (size_t)s * 16 * NSEQ * HD;
    #pragma unroll
    for (int j4 = 0; j4 < 4; ++j4) {
      const float4 v = *reinterpret_cast<const float4*>(p + j4 * 4);
      acc[j4 * 4 + 0] += v.x; acc[j4 * 4 + 1] += v.y;
      acc[j4 * 4 + 2] += v.z; acc[j4 * 4 + 3] += v.w;
    }
    l += Lp[(size_t)s * 16 * NSEQ + (size_t)bh * NSEQ + qq];
  }
  const float il = 1.f / l;
  unsigned short* dst = xa + ((size_t)b * NSEQ + qq) * CCH + h * HD + half * 16;
  uint4 w0, w1;
  w0.x = pk_bf_rnd(acc[0] * il,  acc[1] * il);
  w0.y = pk_bf_rnd(acc[2] * il,  acc[3] * il);
  w0.z = pk_bf_rnd(acc[4] * il,  acc[5] * il);
  w0.w = pk_bf_rnd(acc[6] * il,  acc[7] * il);
  w1.x = pk_bf_rnd(acc[8] * il,  acc[9] * il);
  w1.y = pk_bf_rnd(acc[10] * il, acc[11] * il);
  w1.z = pk_bf_rnd(acc[12] * il, acc[13] * il);
  w1.w = pk_bf_rnd(acc[14] * il, acc[15] * il);
  *reinterpret_cast<uint4*>(dst)     = w0;
  *reinterpret_cast<uint4*>(dst + 8) = w1;
}

extern "C" void kernel_launch(void* const* d_in, const int* in_sizes, int n_in,
                              void* d_out, int out_size, void* d_ws, size_t ws_size,
                              hipStream_t stream) {
  const float* x      = (const float*)d_in[0];
  const float* norm_w = (const float*)d_in[1];
  const float* norm_b = (const float*)d_in[2];
  const float* qkv_w  = (const float*)d_in[3];
  const float* qkv_b  = (const float*)d_in[4];
  const float* proj_w = (const float*)d_in[5];
  const float* proj_b = (const float*)d_in[6];
  const float* gamma  = (const float*)d_in[7];
  float* out = (float*)d_out;

  char* ws = (char*)d_ws;
  unsigned short* xn  = (unsigned short*)(ws);              // (B,N,C) bf16, 4 MiB
  unsigned short* qwb = (unsigned short*)(ws + 4194304);
  unsigned short* pwb = (unsigned short*)(ws + 4587520);
  unsigned short* q   = (unsigned short*)(ws + 4718592);    // (B,NH,N,HD), pre-scaled
  unsigned short* k   = (unsigned short*)(ws + 8912896);    // (B,NH,N,HD)
  unsigned short* vt  = (unsigned short*)(ws + 13107200);   // (B,NH,HD,N)
  unsigned short* xa  = (unsigned short*)(ws + 17301504);   // (B,N,C)
  const size_t part_off = 21495808;
  const size_t o_per_split = (size_t)16 * NSEQ * HD * 4;    // 8 MiB
  const size_t l_per_split = (size_t)16 * NSEQ * 4;         // 256 KiB

  int S = 1;
  if (ws_size >= part_off + 4 * (o_per_split + l_per_split))      S = 4;
  else if (ws_size >= part_off + 2 * (o_per_split + l_per_split)) S = 2;
  float* Op = (float*)(ws + part_off);
  float* Lp = (float*)(ws + part_off + (size_t)S * o_per_split);

  hipLaunchKernelGGL(cvt_weights, dim3(256), dim3(256), 0, stream, qkv_w, proj_w, qwb, pwb);
  hipLaunchKernelGGL(ln_kernel,   dim3(256), dim3(256), 0, stream, x, norm_w, norm_b, xn);
  hipLaunchKernelGGL(qkv_gemm,    dim3(64, 12), dim3(256), 0, stream, xn, qwb, qkv_b, q, k, vt);
  if (S == 4) {
    fa_kernel<4><<<dim3(2048), dim3(256), 0, stream>>>(q, k, vt, xa, Op, Lp);
    hipLaunchKernelGGL(fa_combine, dim3(512), dim3(256), 0, stream, Op, Lp, xa, 4);
  } else if (S == 2) {
    fa_kernel<2><<<dim3(1024), dim3(256), 0, stream>>>(q, k, vt, xa, Op, Lp);
    hipLaunchKernelGGL(fa_combine, dim3(512), dim3(256), 0, stream, Op, Lp, xa, 2);
  } else {
    fa_kernel<1><<<dim3(512), dim3(256), 0, stream>>>(q, k, vt, xa, Op, Lp);
  }
  hipLaunchKernelGGL(proj_gemm,   dim3(64, 4), dim3(256), 0, stream, xa, pwb, proj_b, gamma, x, out);
}

// Round 6
// 181.879 us; speedup vs baseline: 1.3510x; 1.0597x over previous
//
#include <hip/hip_runtime.h>

#define CCH   256
#define NSEQ  4096
#define NH    8
#define HD    32

typedef short s8x __attribute__((ext_vector_type(8)));
typedef float f4x __attribute__((ext_vector_type(4)));

__device__ __forceinline__ f4x mfma16(s8x a, s8x b, f4x c) {
  return __builtin_amdgcn_mfma_f32_16x16x32_bf16(a, b, c, 0, 0, 0);
}

__device__ __forceinline__ unsigned short f2bf(float f) {
  union { float f; unsigned int u; } v; v.f = f;
  unsigned int u = v.u + 0x7fffu + ((v.u >> 16) & 1u);
  return (unsigned short)(u >> 16);
}

__device__ __forceinline__ unsigned int pk_bf_rnd(float lo, float hi) {
  return (unsigned int)f2bf(lo) | ((unsigned int)f2bf(hi) << 16);
}

// pack two f32 -> one u32 of bf16 (truncating; P >= 0 so safe)
__device__ __forceinline__ unsigned int pk_bf_trunc(float lo, float hi) {
  union { float f; unsigned int u; } a, b; a.f = lo; b.f = hi;
  return __builtin_amdgcn_perm(b.u, a.u, 0x07060302);
}

// raw v_exp_f32
#if defined(__has_builtin)
#if __has_builtin(__builtin_amdgcn_exp2f)
#define FEXP2(x) __builtin_amdgcn_exp2f(x)
#endif
#endif
#ifndef FEXP2
__device__ __forceinline__ float __fexp2_asm(float x) {
  float r; asm("v_exp_f32 %0, %1" : "=v"(r) : "v"(x)); return r;
}
#define FEXP2(x) __fexp2_asm(x)
#endif

#define C2SCALE (0.17677669529663689f * 1.4426950408889634f)

// ---------------- LayerNorm + transpose, with cvt_weights folded in ----------------
// blocks 0..255: ln (32 positions each); blocks 256..511: weight fp32->bf16.
__global__ __launch_bounds__(256) void ln_cvt_kernel(const float* __restrict__ x,
                                                     const float* __restrict__ nw,
                                                     const float* __restrict__ nb,
                                                     unsigned short* __restrict__ xn,
                                                     const float* __restrict__ qw,
                                                     const float* __restrict__ pw,
                                                     unsigned short* __restrict__ qwb,
                                                     unsigned short* __restrict__ pwb) {
  if (blockIdx.x >= 256) {
    const int t = (blockIdx.x - 256) * 256 + threadIdx.x;   // 0..65535
    const float4* src;
    unsigned short* dst;
    int idx;
    if (t < 49152) { src = reinterpret_cast<const float4*>(qw); dst = qwb; idx = t; }
    else           { src = reinterpret_cast<const float4*>(pw); dst = pwb; idx = t - 49152; }
    const float4 vv = src[idx];
    union { unsigned short u[4]; uint2 v; } pk;
    pk.u[0] = f2bf(vv.x); pk.u[1] = f2bf(vv.y); pk.u[2] = f2bf(vv.z); pk.u[3] = f2bf(vv.w);
    *reinterpret_cast<uint2*>(dst + 4 * idx) = pk.v;
    return;
  }

  __shared__ float Ls[256 * 32];
  __shared__ float Sred[2][32][8];
  const int t  = threadIdx.x;
  const int n  = t & 31;
  const int cg = t >> 5;
  const int p0 = blockIdx.x * 32;
  const int b  = p0 >> 12;
  const int n0 = p0 & 4095;
  const float* xb = x + (size_t)b * CCH * NSEQ + n0;

  #pragma unroll
  for (int i = 0; i < 32; ++i) {
    const int c = i * 8 + cg;
    Ls[c * 32 + (n ^ (c & 31))] = xb[(size_t)c * NSEQ + n];
  }
  __syncthreads();

  float s = 0.f, sq = 0.f;
  #pragma unroll
  for (int j = 0; j < 32; ++j) {
    const int c = cg * 32 + j;
    const float v = Ls[c * 32 + (n ^ j)];
    s += v; sq += v * v;
  }
  Sred[0][n][cg] = s; Sred[1][n][cg] = sq;
  __syncthreads();
  float ts = 0.f, tq = 0.f;
  #pragma unroll
  for (int g = 0; g < 8; ++g) { ts += Sred[0][n][g]; tq += Sred[1][n][g]; }
  const float mean = ts * (1.f / 256.f);
  const float rstd = rsqrtf(tq * (1.f / 256.f) - mean * mean + 1e-5f);

  unsigned short* orow = xn + ((size_t)b * NSEQ + n0 + n) * CCH + cg * 32;
  #pragma unroll
  for (int j8 = 0; j8 < 4; ++j8) {
    unsigned int w_[4];
    #pragma unroll
    for (int hw = 0; hw < 4; ++hw) {
      const int j = j8 * 8 + hw * 2;
      const int c = cg * 32 + j;
      const float v0 = Ls[c * 32 + (n ^ j)];
      const float v1 = Ls[(c + 1) * 32 + (n ^ (j + 1))];
      const float y0 = (v0 - mean) * rstd * nw[c] + nb[c];
      const float y1 = (v1 - mean) * rstd * nw[c + 1] + nb[c + 1];
      w_[hw] = pk_bf_rnd(y0, y1);
    }
    uint4 pkv; pkv.x = w_[0]; pkv.y = w_[1]; pkv.z = w_[2]; pkv.w = w_[3];
    *reinterpret_cast<uint4*>(orow + j8 * 8) = pkv;
  }
}

// ======== shared LDS-tiled GEMM core: 128m x 64n tile, BK=64, K=256 ========
#define GEMM_CORE(A_PTR, B_PTR, ACC)                                            \
  {                                                                             \
    for (int kb = 0; kb < 4; ++kb) {                                            \
      if (kb) __syncthreads();                                                  \
      _Pragma("unroll")                                                         \
      for (int j = 0; j < 4; ++j) {                                             \
        const int c = j * 256 + tid;                                            \
        const int ar = c >> 3, acr = c & 7;                                     \
        *reinterpret_cast<s8x*>(&As[ar * 64 + ((acr ^ (ar & 7)) << 3)]) =       \
          *reinterpret_cast<const s8x*>(A_PTR + (size_t)(mt * 128 + ar) * CCH + kb * 64 + acr * 8); \
      }                                                                         \
      _Pragma("unroll")                                                         \
      for (int j = 0; j < 2; ++j) {                                             \
        const int c = j * 256 + tid;                                            \
        const int br = c >> 3, bcr = c & 7;                                     \
        *reinterpret_cast<s8x*>(&Bs[br * 64 + ((bcr ^ (br & 7)) << 3)]) =       \
          *reinterpret_cast<const s8x*>(B_PTR + (size_t)(nt * 64 + br) * CCH + kb * 64 + bcr * 8); \
      }                                                                         \
      __syncthreads();                                                          \
      _Pragma("unroll")                                                         \
      for (int kin = 0; kin < 2; ++kin) {                                       \
        const int chx = ((kin * 4 + quad) ^ (l16 & 7)) << 3;                    \
        const s8x a0 = *reinterpret_cast<const s8x*>(&As[(wv * 32 + l16) * 64 + chx]);      \
        const s8x a1 = *reinterpret_cast<const s8x*>(&As[(wv * 32 + 16 + l16) * 64 + chx]); \
        _Pragma("unroll")                                                       \
        for (int ni = 0; ni < 4; ++ni) {                                        \
          const s8x bf = *reinterpret_cast<const s8x*>(&Bs[(ni * 16 + l16) * 64 + chx]);    \
          ACC[0][ni] = mfma16(a0, bf, ACC[0][ni]);                              \
          ACC[1][ni] = mfma16(a1, bf, ACC[1][ni]);                              \
        }                                                                       \
      }                                                                         \
    }                                                                           \
  }

// ---------------- QKV GEMM (tiled) ----------------
__global__ __launch_bounds__(256, 3) void qkv_gemm(const unsigned short* __restrict__ xn,
                                                   const unsigned short* __restrict__ w,
                                                   const float* __restrict__ bias,
                                                   unsigned short* __restrict__ q,
                                                   unsigned short* __restrict__ k,
                                                   unsigned short* __restrict__ vt) {
  __shared__ unsigned short As[128 * 64];
  __shared__ unsigned short Bs[64 * 64];
  const int tid = threadIdx.x;
  const int wv  = tid >> 6;
  const int lane = tid & 63;
  const int quad = lane >> 4, l16 = lane & 15;
  const int mt = blockIdx.x;
  const int nt = blockIdx.y;

  f4x acc[2][4];
  #pragma unroll
  for (int mi = 0; mi < 2; ++mi)
    #pragma unroll
    for (int ni = 0; ni < 4; ++ni)
      acc[mi][ni] = (f4x){0.f, 0.f, 0.f, 0.f};

  GEMM_CORE(xn, w, acc)

  const int sel = nt >> 2;                  // wave-uniform: 0=q 1=k 2=v
  #pragma unroll
  for (int ni = 0; ni < 4; ++ni) {
    const int o = nt * 64 + ni * 16 + l16;
    const float bs = bias[o];
    const int ol = o & 255;
    const int head = ol >> 5, d = ol & 31;
    #pragma unroll
    for (int mi = 0; mi < 2; ++mi) {
      const int g0 = mt * 128 + wv * 32 + mi * 16 + quad * 4;
      const int bb = g0 >> 12, n0 = g0 & 4095;
      if (sel == 2) {
        unsigned short* vp = vt + ((size_t)(bb * NH + head) * HD + d) * NSEQ + n0;
        uint2 pk;
        pk.x = pk_bf_rnd(acc[mi][ni][0] + bs, acc[mi][ni][1] + bs);
        pk.y = pk_bf_rnd(acc[mi][ni][2] + bs, acc[mi][ni][3] + bs);
        *reinterpret_cast<uint2*>(vp) = pk;
      } else {
        const float sc = (sel == 0) ? C2SCALE : 1.f;
        unsigned short* base = (sel == 0) ? q : k;
        #pragma unroll
        for (int r = 0; r < 4; ++r)
          base[((size_t)(bb * NH + head) * NSEQ + n0 + r) * HD + d] = f2bf((acc[mi][ni][r] + bs) * sc);
      }
    }
  }
}

// ---------------- proj GEMM + residual (tiled) ----------------
__global__ __launch_bounds__(256, 3) void proj_gemm(const unsigned short* __restrict__ xa,
                                                    const unsigned short* __restrict__ w,
                                                    const float* __restrict__ bias,
                                                    const float* __restrict__ gamma,
                                                    const float* __restrict__ x,
                                                    float* __restrict__ out) {
  __shared__ unsigned short As[128 * 64];
  __shared__ unsigned short Bs[64 * 64];
  const int tid = threadIdx.x;
  const int wv  = tid >> 6;
  const int lane = tid & 63;
  const int quad = lane >> 4, l16 = lane & 15;
  const int mt = blockIdx.x;
  const int nt = blockIdx.y;

  f4x acc[2][4];
  #pragma unroll
  for (int mi = 0; mi < 2; ++mi)
    #pragma unroll
    for (int ni = 0; ni < 4; ++ni)
      acc[mi][ni] = (f4x){0.f, 0.f, 0.f, 0.f};

  GEMM_CORE(xa, w, acc)

  const float g0 = gamma[0];
  #pragma unroll
  for (int ni = 0; ni < 4; ++ni) {
    const int c = nt * 64 + ni * 16 + l16;
    const float bs = bias[c];
    #pragma unroll
    for (int mi = 0; mi < 2; ++mi) {
      const int gr = mt * 128 + wv * 32 + mi * 16 + quad * 4;
      const int bb = gr >> 12, n0 = gr & 4095;
      const size_t off = (size_t)(bb * CCH + c) * NSEQ + n0;
      const float4 xv = *reinterpret_cast<const float4*>(x + off);
      float4 ov;
      ov.x = g0 * (acc[mi][ni][0] + bs) + xv.x;
      ov.y = g0 * (acc[mi][ni][1] + bs) + xv.y;
      ov.z = g0 * (acc[mi][ni][2] + bs) + xv.z;
      ov.w = g0 * (acc[mi][ni][3] + bs) + xv.w;
      *reinterpret_cast<float4*>(out + off) = ov;
    }
  }
}

// ---------------- Flash attention (software-pipelined, barrier-free) ----------------
// 512 blocks (bh = i&15 -> XCD pinning), 256 thr = 4 waves, wave owns 32 q-cols.
// Pipeline per iter: exp+pack+writeP(it) || S-mfma(it+1) || ak-prefetch(it+2)
//   -> PV(it) -> av-prefetch(it+1).  Independent VALU/MFMA/VMEM streams let the
// compiler interleave pipes within one wave (occupancy is register-capped at
// 2 waves/SIMD -- measured R5 -- so intra-wave ILP is the only lever).
// Ps rows padded to 136 shorts: bank-uniform for b64 writes and b128 reads.
__global__ __launch_bounds__(256, 2) void fa_kernel(const unsigned short* __restrict__ q,
                                                    const unsigned short* __restrict__ k,
                                                    const unsigned short* __restrict__ vt,
                                                    unsigned short* __restrict__ xa) {
  __shared__ unsigned short Ps[128 * 136];   // 34 KiB, padded rows

  const int tid  = threadIdx.x;
  const int wv   = tid >> 6;
  const int lane = tid & 63;
  const int quad = lane >> 4;
  const int l16  = lane & 15;
  const int i    = blockIdx.x;
  const int bh   = i & 15;
  const int qblk = i >> 4;
  const int b    = bh >> 3;
  const int h    = bh & 7;

  const unsigned short* kb_ = k  + (size_t)bh * NSEQ * HD;
  const unsigned short* vb_ = vt + (size_t)bh * HD * NSEQ;

  s8x bq0, bq1;
  {
    const unsigned short* qb = q + ((size_t)bh * NSEQ + (size_t)qblk * 128 + wv * 32) * HD;
    bq0 = *reinterpret_cast<const s8x*>(qb + (size_t)l16 * HD + quad * 8);
    bq1 = *reinterpret_cast<const s8x*>(qb + (size_t)(16 + l16) * HD + quad * 8);
  }
  s8x ak[8];
  #pragma unroll
  for (int ii = 0; ii < 8; ++ii)
    ak[ii] = *reinterpret_cast<const s8x*>(kb_ + (size_t)(ii * 16 + l16) * HD + quad * 8);
  s8x av[8];
  #pragma unroll
  for (int kb2 = 0; kb2 < 4; ++kb2) {
    av[kb2]     = *reinterpret_cast<const s8x*>(vb_ + (size_t)l16 * NSEQ + kb2 * 32 + quad * 8);
    av[4 + kb2] = *reinterpret_cast<const s8x*>(vb_ + (size_t)(16 + l16) * NSEQ + kb2 * 32 + quad * 8);
  }

  // S(0), then refill ak with tile 1
  f4x st[8][2];
  #pragma unroll
  for (int ii = 0; ii < 8; ++ii) {
    const f4x z = {0.f, 0.f, 0.f, 0.f};
    st[ii][0] = mfma16(ak[ii], bq0, z);
    st[ii][1] = mfma16(ak[ii], bq1, z);
  }
  #pragma unroll
  for (int ii = 0; ii < 8; ++ii)
    ak[ii] = *reinterpret_cast<const s8x*>(kb_ + (size_t)(128 + ii * 16 + l16) * HD + quad * 8);

  f4x oacc[2][2];
  #pragma unroll
  for (int dt = 0; dt < 2; ++dt)
    #pragma unroll
    for (int ct = 0; ct < 2; ++ct)
      oacc[dt][ct] = (f4x){0.f, 0.f, 0.f, 0.f};
  f4x accL[2] = {(f4x){0.f, 0.f, 0.f, 0.f}, (f4x){0.f, 0.f, 0.f, 0.f}};

  s8x ones;
  #pragma unroll
  for (int j = 0; j < 8; ++j) ones[j] = (short)0x3F80;   // bf16 1.0

  const int r0 = (wv * 32 + l16) * 136;
  const int r1 = (wv * 32 + 16 + l16) * 136;

  for (int it = 0; it < NSEQ / 128; ++it) {
    // ---- exp + pack + write P(it): VALU + LDS-write stream ----
    #pragma unroll
    for (int ct = 0; ct < 2; ++ct) {
      const int prow = (wv * 32 + ct * 16 + l16) * 136;
      #pragma unroll
      for (int ii = 0; ii < 8; ++ii) {
        const float e0 = FEXP2(st[ii][ct][0]);
        const float e1 = FEXP2(st[ii][ct][1]);
        const float e2 = FEXP2(st[ii][ct][2]);
        const float e3 = FEXP2(st[ii][ct][3]);
        uint2 pw;
        pw.x = pk_bf_trunc(e0, e1);
        pw.y = pk_bf_trunc(e2, e3);
        *reinterpret_cast<uint2*>(&Ps[prow + ii * 16 + quad * 4]) = pw;
      }
    }

    // ---- S(it+1): independent MFMA stream (interleaves with exp above) ----
    if (it + 1 < NSEQ / 128) {
      #pragma unroll
      for (int ii = 0; ii < 8; ++ii) {
        const f4x z = {0.f, 0.f, 0.f, 0.f};
        st[ii][0] = mfma16(ak[ii], bq0, z);
        st[ii][1] = mfma16(ak[ii], bq1, z);
      }
    }
    // ---- prefetch K(it+2): VMEM stream, 2 iters ahead of use ----
    if (it + 2 < NSEQ / 128) {
      const unsigned short* kn = kb_ + (size_t)(it + 2) * 128 * HD;
      #pragma unroll
      for (int ii = 0; ii < 8; ++ii)
        ak[ii] = *reinterpret_cast<const s8x*>(kn + (size_t)(ii * 16 + l16) * HD + quad * 8);
    }

    // ---- PV(it) + l-accum: LDS-read + MFMA ----
    #pragma unroll
    for (int kb2 = 0; kb2 < 4; ++kb2) {
      const s8x bp0 = *reinterpret_cast<const s8x*>(&Ps[r0 + kb2 * 32 + quad * 8]);
      const s8x bp1 = *reinterpret_cast<const s8x*>(&Ps[r1 + kb2 * 32 + quad * 8]);
      oacc[0][0] = mfma16(av[kb2],     bp0, oacc[0][0]);
      oacc[1][0] = mfma16(av[4 + kb2], bp0, oacc[1][0]);
      oacc[0][1] = mfma16(av[kb2],     bp1, oacc[0][1]);
      oacc[1][1] = mfma16(av[4 + kb2], bp1, oacc[1][1]);
      accL[0] = mfma16(ones, bp0, accL[0]);
      accL[1] = mfma16(ones, bp1, accL[1]);
    }

    // ---- prefetch V^T(it+1) ----
    if (it + 1 < NSEQ / 128) {
      const unsigned short* vn = vb_ + (size_t)(it + 1) * 128;
      #pragma unroll
      for (int kb2 = 0; kb2 < 4; ++kb2) {
        av[kb2]     = *reinterpret_cast<const s8x*>(vn + (size_t)l16 * NSEQ + kb2 * 32 + quad * 8);
        av[4 + kb2] = *reinterpret_cast<const s8x*>(vn + (size_t)(16 + l16) * NSEQ + kb2 * 32 + quad * 8);
      }
    }
  }

  // ---- epilogue: O/l ; store xa (B,N,C) bf16 ----
  #pragma unroll
  for (int ct = 0; ct < 2; ++ct) {
    const float il = 1.f / accL[ct][0];
    const int qg = qblk * 128 + wv * 32 + ct * 16 + l16;
    #pragma unroll
    for (int dt = 0; dt < 2; ++dt) {
      uint2 ow;
      ow.x = pk_bf_rnd(oacc[dt][ct][0] * il, oacc[dt][ct][1] * il);
      ow.y = pk_bf_rnd(oacc[dt][ct][2] * il, oacc[dt][ct][3] * il);
      unsigned short* dst = xa + ((size_t)b * NSEQ + qg) * CCH + h * HD + dt * 16 + quad * 4;
      *reinterpret_cast<uint2*>(dst) = ow;
    }
  }
}

extern "C" void kernel_launch(void* const* d_in, const int* in_sizes, int n_in,
                              void* d_out, int out_size, void* d_ws, size_t ws_size,
                              hipStream_t stream) {
  const float* x      = (const float*)d_in[0];
  const float* norm_w = (const float*)d_in[1];
  const float* norm_b = (const float*)d_in[2];
  const float* qkv_w  = (const float*)d_in[3];
  const float* qkv_b  = (const float*)d_in[4];
  const float* proj_w = (const float*)d_in[5];
  const float* proj_b = (const float*)d_in[6];
  const float* gamma  = (const float*)d_in[7];
  float* out = (float*)d_out;

  char* ws = (char*)d_ws;
  unsigned short* xn  = (unsigned short*)(ws);              // (B,N,C) bf16, 4 MiB
  unsigned short* qwb = (unsigned short*)(ws + 4194304);
  unsigned short* pwb = (unsigned short*)(ws + 4587520);
  unsigned short* q   = (unsigned short*)(ws + 4718592);    // (B,NH,N,HD), pre-scaled
  unsigned short* k   = (unsigned short*)(ws + 8912896);    // (B,NH,N,HD)
  unsigned short* vt  = (unsigned short*)(ws + 13107200);   // (B,NH,HD,N)
  unsigned short* xa  = (unsigned short*)(ws + 17301504);   // (B,N,C)

  hipLaunchKernelGGL(ln_cvt_kernel, dim3(512), dim3(256), 0, stream,
                     x, norm_w, norm_b, xn, qkv_w, proj_w, qwb, pwb);
  hipLaunchKernelGGL(qkv_gemm,  dim3(64, 12), dim3(256), 0, stream, xn, qwb, qkv_b, q, k, vt);
  hipLaunchKernelGGL(fa_kernel, dim3(512), dim3(256), 0, stream, q, k, vt, xa);
  hipLaunchKernelGGL(proj_gemm, dim3(64, 4), dim3(256), 0, stream, xa, pwb, proj_b, gamma, x, out);
}